// Round 1
// baseline (234.750 us; speedup 1.0000x reference)
//
#include <hip/hip_runtime.h>
#include <math.h>

// Match numpy's separate mul/add roundings — no FMA contraction anywhere.
#pragma clang fp contract(off)

#define TPB 256
#define ROWLEN 1024

// One block per row of 1024 f32. Each thread owns 4 consecutive elements
// (float4). All sensitive arithmetic in f64 mirroring the numpy reference's
// evaluation order. Row sum of exp_int is an exact integer in f64 (values
// <= ~3.7e10 < 2^53), so `factor = floor(2^32/sum)` is order-independent
// and matches the reference exactly — the one quantity whose floor-flip
// would exceed the absmax threshold.
__global__ __launch_bounds__(TPB) void qsplit_int_softmax_kernel(
    const float* __restrict__ x,
    const float* __restrict__ scale_p,
    const float* __restrict__ thr_p,
    float* __restrict__ out)
{
    const int row = blockIdx.x;
    const int tid = threadIdx.x;
    const size_t base = (size_t)row * ROWLEN + (size_t)tid * 4;

    const float4 xv = *(const float4*)(x + base);

    const double sf  = (double)scale_p[0];   // 0.05f widened
    const double thr = (double)thr_p[0];     // 0.1f widened

    // Constants (uniform per kernel; cheap per-thread).
    const double rsf    = 1.0 / sf;
    const double x0_int = floor(-0.69314718 / sf);                       // -14
    const double b_int  = floor((0.96963238 / 0.35815147) / sf);         // 54
    const double c_int  = floor((1.0 / 0.35815147) / (sf * sf));         // 1116
    const double clampv = 15.0 * x0_int;                                 // -210
    const double inv_x0 = 1.0 / x0_int;

    double xiv[4];
    xiv[0] = (double)xv.x * rsf;
    xiv[1] = (double)xv.y * rsf;
    xiv[2] = (double)xv.z * rsf;
    xiv[3] = (double)xv.w * rsf;

    // ---- block max reduce (butterfly within wave64, LDS across 4 waves) ----
    double m = fmax(fmax(xiv[0], xiv[1]), fmax(xiv[2], xiv[3]));
    #pragma unroll
    for (int off = 1; off < 64; off <<= 1)
        m = fmax(m, __shfl_xor(m, off));

    __shared__ double sred[2][4];
    const int wave = tid >> 6;
    if ((tid & 63) == 0) sred[0][wave] = m;
    __syncthreads();
    m = fmax(fmax(sred[0][0], sred[0][1]), fmax(sred[0][2], sred[0][3]));

    // ---- per-element integer exp ----
    double e[4];
    double lsum = 0.0;
    #pragma unroll
    for (int j = 0; j < 4; ++j) {
        double v = xiv[j] - m;          // <= 0
        v = fmax(v, clampv);            // >= -210
        // q = floor(v / x0_int); v<=0, inv_x0<0 -> product >=0, trunc==floor.
        int qi = (int)(v * inv_x0);
        if (qi > 15) qi = 15;           // guard 1-ulp overshoot at the clamp
        double r = v - x0_int * (double)qi;   // exact (14*qi integer, Sterbenz-safe)
        double t = r + b_int;
        double z = r * t + c_int;             // two roundings, contraction off
        double pw = (double)(1 << (15 - qi)); // exact power of two
        double ei = floor(z * pw);            // pow2 scale: exact, floor exact
        ei = fmax(ei, 0.0);
        e[j] = ei;
        lsum += ei;                           // exact integer accumulation
    }

    // ---- block sum reduce ----
    #pragma unroll
    for (int off = 1; off < 64; off <<= 1)
        lsum += __shfl_xor(lsum, off);
    if ((tid & 63) == 0) sred[1][wave] = lsum;
    __syncthreads();
    const double s = (sred[1][0] + sred[1][1]) + (sred[1][2] + sred[1][3]); // exact

    // ---- epilogue scales (mirror numpy expression order) ----
    const double factor = floor(4294967296.0 / s);
    const double osA  = thr / 255.0;
    const double osB  = 1.0 / 255.0;
    const double denA = 4294967296.0 * osA;
    const double denB = 4294967296.0 * osB;
    const double invDenA = 1.0 / denA;   // reciprocal: floor-flip risk ~1e-13/elem
    const double invDenB = 1.0 / denB;
    const double ath  = (floor(thr * 256.0) * s) * (1.0 / 256.0); // 25*s exact, /256 exact

    float4 o;
    float res[4];
    #pragma unroll
    for (int j = 0; j < 4; ++j) {
        const double ei = e[j];
        const bool isA = (ei <= ath);
        const double numer = ei * factor;     // exact: <= 2^32 < 2^53
        double sA = 0.0, sB = 0.0;
        if (isA) {
            sA = floor(numer * invDenA);
        } else {
            sB = fmin(floor(numer * invDenB), 255.0);
        }
        res[j] = (float)(sA * osA + sB * osB);
    }
    o.x = res[0]; o.y = res[1]; o.z = res[2]; o.w = res[3];
    *(float4*)(out + base) = o;
}

extern "C" void kernel_launch(void* const* d_in, const int* in_sizes, int n_in,
                              void* d_out, int out_size, void* d_ws, size_t ws_size,
                              hipStream_t stream) {
    const float* x     = (const float*)d_in[0];
    const float* scale = (const float*)d_in[1];
    const float* thr   = (const float*)d_in[2];
    float* out = (float*)d_out;

    const int total = in_sizes[0];        // 2*16*1024*1024 = 33554432
    const int rows  = total / ROWLEN;     // 32768

    qsplit_int_softmax_kernel<<<dim3(rows), dim3(TPB), 0, stream>>>(
        x, scale, thr, out);
}

// Round 2
// 231.620 us; speedup vs baseline: 1.0135x; 1.0135x over previous
//
#include <hip/hip_runtime.h>
#include <math.h>

// Match numpy's separate mul/add roundings — no FMA contraction anywhere.
#pragma clang fp contract(off)

#define TPB 256
#define ROWLEN 1024

// One WAVE per row of 1024 f32 (64 lanes x 16 elements). 4 rows per block.
// No LDS, no __syncthreads — wave shuffle reductions only.
//
// Precision strategy: the numpy reference is float32 throughout, so the
// element-wise path is f32 and bit-matches numpy except at provably-benign
// boundaries:
//  - x/sf and the epilogue divisions are emulated as (float)((double)a * inv_d)
//    == correctly-rounded f32 division except ~1e-16-relative corners.
//  - q = floor(x_int/x0_int) via f32 reciprocal-mul: flips only at integer
//    quotients, where the I-BERT polynomial is continuous within 0.4%
//    (z(0)=1116 vs 2*z(-14)=1112) -> at most +-1 output quantum.
//  - The row sum of exp_int is accumulated in f64: exact integer (<=3.7e10
//    < 2^53), order-independent. Protects factor=floor(2^32/sum), whose
//    floor-flip would be the one catastrophic error. Round-1 empirically
//    confirmed the exact sum matches numpy's pairwise-f32 sum here.
__global__ __launch_bounds__(TPB) void qsplit_int_softmax_kernel(
    const float* __restrict__ x,
    const float* __restrict__ scale_p,
    const float* __restrict__ thr_p,
    float* __restrict__ out)
{
    const int lane = threadIdx.x & 63;
    const int wid  = threadIdx.x >> 6;
    const int row  = blockIdx.x * 4 + wid;
    const size_t rbase = (size_t)row * ROWLEN + (size_t)lane * 4;

    const float  sf   = scale_p[0];     // 0.05f
    const float  thr  = thr_p[0];       // 0.1f
    const double sfd  = (double)sf;
    const double rsfd = 1.0 / sfd;

    // Reference-mirroring integer constants (floors far from boundaries).
    const double x0d    = floor(-0.69314718 / sfd);                    // -14
    const float  x0f    = (float)x0d;
    const float  bfc    = (float)floor((0.96963238 / 0.35815147) / sfd);        // 54
    const float  cfc    = (float)floor((1.0 / 0.35815147) / (sfd * sfd));       // 1116
    const float  clampf = (float)(15.0 * x0d);                         // -210
    const float  invx0f = 1.0f / x0f;   // one-time f32 div

    // ---- load 16 elements (4x float4, each instr = 1KB contiguous/wave) ----
    float4 xv[4];
    #pragma unroll
    for (int k = 0; k < 4; ++k)
        xv[k] = *(const float4*)(x + rbase + (size_t)k * 256);

    // ---- x_int = x/sf (emulated correctly-rounded f32 division) ----
    float xi[16];
    #pragma unroll
    for (int k = 0; k < 4; ++k) {
        xi[k*4+0] = (float)((double)xv[k].x * rsfd);
        xi[k*4+1] = (float)((double)xv[k].y * rsfd);
        xi[k*4+2] = (float)((double)xv[k].z * rsfd);
        xi[k*4+3] = (float)((double)xv[k].w * rsfd);
    }

    // ---- wave max (f32, exact & order-independent) ----
    float m = xi[0];
    #pragma unroll
    for (int j = 1; j < 16; ++j) m = fmaxf(m, xi[j]);
    #pragma unroll
    for (int off = 1; off < 64; off <<= 1)
        m = fmaxf(m, __shfl_xor(m, off));

    // ---- integer exp per element (all f32, bit-matching numpy) ----
    float e[16];
    double lsum = 0.0;
    #pragma unroll
    for (int j = 0; j < 16; ++j) {
        float v = xi[j] - m;                 // exact f32 sub, same as numpy
        v = fmaxf(v, clampf);                // >= -210
        float qf = floorf(v * invx0f);       // recip-mul; flips benign (see top)
        int   ki = 15 - (int)qf;             // in [0,15]
        float r  = v - x0f * qf;             // mul+sub, separate roundings
        float t  = r + bfc;
        float z  = r * t + cfc;              // contract(off): two roundings
        float ei = floorf(ldexpf(z, ki));    // z*2^ki exact; floor exact
        ei = fmaxf(ei, 0.0f);
        e[j] = ei;
        lsum += (double)ei;                  // exact integer accumulation
    }

    // ---- wave sum (f64, exact -> order-independent) ----
    #pragma unroll
    for (int off = 1; off < 64; off <<= 1)
        lsum += __shfl_xor(lsum, off);
    const double s = lsum;

    // ---- row-uniform epilogue scales ----
    const double factor_d = floor(4294967296.0 / s);
    const float  fac_f = (float)factor_d;                  // small int, exact
    const double ath   = (floor((double)thr * 256.0) * s) * (1.0 / 256.0);

    const float  osA  = thr / 255.0f;                      // one-time f32 div
    const float  osB  = 1.0f / 255.0f;
    const float  denA = 4294967296.0f * osA;               // == numpy's f32 den
    const float  denB = 4294967296.0f * osB;
    const double invA = 1.0 / (double)denA;
    const double invB = 1.0 / (double)denB;

    // ---- per-element quantize + store ----
    #pragma unroll
    for (int k = 0; k < 4; ++k) {
        float res[4];
        #pragma unroll
        for (int jj = 0; jj < 4; ++jj) {
            const float ei  = e[k*4+jj];
            const bool  isA = ((double)ei <= ath);
            const float numer = ei * fac_f;                // f32 round, as numpy
            const double inv  = isA ? invA : invB;
            const float  qf2  = (float)((double)numer * inv); // ~= f32 div
            float si = floorf(qf2);
            si = fminf(si, isA ? 3.0e38f : 255.0f);
            res[jj] = si * (isA ? osA : osB);
        }
        float4 o; o.x = res[0]; o.y = res[1]; o.z = res[2]; o.w = res[3];
        *(float4*)(out + rbase + (size_t)k * 256) = o;
    }
}

extern "C" void kernel_launch(void* const* d_in, const int* in_sizes, int n_in,
                              void* d_out, int out_size, void* d_ws, size_t ws_size,
                              hipStream_t stream) {
    const float* x     = (const float*)d_in[0];
    const float* scale = (const float*)d_in[1];
    const float* thr   = (const float*)d_in[2];
    float* out = (float*)d_out;

    const int total = in_sizes[0];        // 2*16*1024*1024
    const int rows  = total / ROWLEN;     // 32768
    const int blocks = rows / 4;          // 4 rows (waves) per block

    qsplit_int_softmax_kernel<<<dim3(blocks), dim3(TPB), 0, stream>>>(
        x, scale, thr, out);
}